// Round 5
// baseline (323.072 us; speedup 1.0000x reference)
//
#include <hip/hip_runtime.h>

typedef unsigned short ushort_t;
typedef __attribute__((ext_vector_type(8))) __bf16 bf16x8;
typedef __attribute__((ext_vector_type(4))) float f32x4;
typedef __attribute__((ext_vector_type(4))) int i32x4;
typedef __attribute__((ext_vector_type(4))) unsigned short u16x4;

#define BN_EPS 1e-5f
#define EPAD 136  // epilogue [p][c] c-stride (272B row, 16B-aligned)

// counted waitcnt via inline asm (no builtin); memory clobber pins VMEM/LDS ops.
// barriers use the builtin (scheduler-aware, does NOT force a vmcnt drain).
#define BAR()    __builtin_amdgcn_s_barrier()
#define VMCNT8() asm volatile("s_waitcnt vmcnt(8)" ::: "memory")
#define VMCNT0() asm volatile("s_waitcnt vmcnt(0)" ::: "memory")
#define LGKM0()  asm volatile("s_waitcnt lgkmcnt(0)" ::: "memory")

__device__ __forceinline__ ushort_t f2bf(float f) {
    union { float f; unsigned u; } v; v.f = f;
    unsigned r = v.u + 0x7FFFu + ((v.u >> 16) & 1u);
    return (ushort_t)(r >> 16);
}
__device__ __forceinline__ float bf2f(ushort_t h) {
    union { unsigned u; float f; } v; v.u = ((unsigned)h) << 16; return v.f;
}

// async 16B global->LDS copy; LDS dst is wave-uniform base (+lane*16 by HW)
__device__ __forceinline__ void async_cp16(const ushort_t* g, ushort_t* l) {
    __builtin_amdgcn_global_load_lds(
        (const __attribute__((address_space(1))) unsigned int*)g,
        (__attribute__((address_space(3))) unsigned int*)l, 16, 0, 0);
}

// ---------------- transpose+cast+GAP: x[b][c][p] f32 -> xt[b][p][c] bf16, partial GAP sums ----------------
__global__ void transpose_gap_kernel(const float* __restrict__ x, ushort_t* __restrict__ xt,
                                     float* __restrict__ gapsum) {
    __shared__ float tile[32][33];
    int b = blockIdx.z, c0 = blockIdx.y * 32, p0 = blockIdx.x * 32;
    int tx = threadIdx.x & 31, ty = threadIdx.x >> 5; // ty 0..7
    float ps[4];
    #pragma unroll
    for (int i = 0; i < 4; ++i) {
        int c = ty + i * 8;
        float v = x[((long)b * 256 + c0 + c) * 1024 + p0 + tx];
        tile[c][tx] = v;
        ps[i] = v;
    }
    #pragma unroll
    for (int off = 16; off; off >>= 1)
        #pragma unroll
        for (int i = 0; i < 4; ++i) ps[i] += __shfl_down(ps[i], off, 32);
    if (tx == 0)
        #pragma unroll
        for (int i = 0; i < 4; ++i) atomicAdd(&gapsum[b * 256 + c0 + ty + i * 8], ps[i]);
    __syncthreads();
    #pragma unroll
    for (int i = 0; i < 4; ++i) {
        int p = ty + i * 8;
        xt[((long)b * 1024 + p0 + p) * 256 + c0 + tx] = f2bf(tile[tx][p]);
    }
}

// ---------------- router linear: r = sigmoid(gap/1024 @ rw^T + rb) ----------------
__global__ void router_linear_kernel(const float* __restrict__ gapsum, const float* __restrict__ rw,
                                     const float* __restrict__ rb, float* __restrict__ r) {
    int t = threadIdx.x, b = t >> 3, e = t & 7;
    float s = 0.f;
    for (int c = 0; c < 256; ++c) s += gapsum[b * 256 + c] * rw[e * 256 + c];
    r[t] = 1.f / (1.f + expf(-(s * (1.f / 1024.f) + rb[e])));
}

// ---------------- combine: ko[b][pos][g] = sum_e r[b,e]*w[e][g][pos], bf16 ----------------
// LDS-staged: block stages a 128-g chunk of w (all 8 e x 9 p = 36.9KB f32) with
// fully-coalesced float4 loads, then each thread owns one g (contiguous 9-float LDS
// run, stride-9-dword = conflict-free), 72 FMA + 9 coalesced 2B stores per b.
__global__ __launch_bounds__(256, 4) void combine_kernel(const float* __restrict__ w,
                                                         const float* __restrict__ r,
                                                         ushort_t* __restrict__ ko) {
    __shared__ float wl[9216]; // [e][128 g * 9 p] raster, 36864 B
    const int t = threadIdx.x;
    const int g0 = blockIdx.x * 128;
    const int b0 = blockIdx.y * 8;

    // stage: 2304 float4 (9216 floats), 9 float4 per thread, coalesced
    #pragma unroll
    for (int it = 0; it < 9; ++it) {
        int lin = it * 256 + t;            // float4 index in chunk
        int e = lin / 288, rem = lin - e * 288;  // 288 float4 per e-section
        f32x4 v = *(const f32x4*)(w + (long)e * 589824 + (long)g0 * 9 + rem * 4);
        *(f32x4*)(&wl[lin * 4]) = v;
    }
    __syncthreads();

    const int g = t & 127;       // owned g within chunk
    const int half = t >> 7;     // 0/1: which 4 of the 8 b's
    float wv[8][9];
    #pragma unroll
    for (int e = 0; e < 8; ++e)
        #pragma unroll
        for (int p = 0; p < 9; ++p)
            wv[e][p] = wl[e * 1152 + g * 9 + p];

    #pragma unroll
    for (int j = 0; j < 4; ++j) {
        int b = b0 + half * 4 + j;
        float rv[8];
        #pragma unroll
        for (int e = 0; e < 8; ++e) rv[e] = r[b * 8 + e];
        #pragma unroll
        for (int p = 0; p < 9; ++p) {
            float s = 0.f;
            #pragma unroll
            for (int e = 0; e < 8; ++e) s += rv[e] * wv[e][p];
            ko[((long)(b * 9 + p)) * 65536 + g0 + g] = f2bf(s);
        }
    }
}

// ---------------- implicit-GEMM conv 3x3 (pad 1), per-sample weights ----------------
// Grid: 512 linear blocks, XCD-swizzled: id%8 = b%8 so all 16 (nt,mt) siblings of a
// sample land on one XCD => weight/x L2 reuse.
// A (weights) path: DIRECT global->VGPR per-fragment loads (16B/lane, the MFMA A
// fragment is contiguous in kbank's i-dim), register double-buffered 1 iter deep.
// No ldsA, no per-iter barriers: LDS holds only the x halo tile (ldsB), republished
// once per kc (4x per kernel). vmcnt(8) at each wait retires exactly {prior A (8) +
// any stageB} since stageB is always issued after the A-prefetch it trails.
// LDS ldsB: halo [6][34] rows x 8 k-chunks; slot(pi,j) = pi*8 + (j ^ (pi&7)) (16B units)
// MODE 0: out = bf16 relu(bn(conv)) [b][p][c];  MODE 1: out = f32 relu(bn(conv)+resid) [b][c][p]
template <int MODE>
__global__ __launch_bounds__(256, 2) void gemm_conv(
    const ushort_t* __restrict__ xin,   // [B][1024][256] bf16
    const ushort_t* __restrict__ kbank, // [B][9][256][256] bf16
    void* __restrict__ outp,
    const float* __restrict__ gam, const float* __restrict__ bet,
    const float* __restrict__ mu, const float* __restrict__ var,
    const ushort_t* __restrict__ residt) { // [B][1024][256] bf16 (MODE 1 only)
    constexpr int SMEMN = (MODE == 0) ? 17408 : 13056; // ldsB needs 13056; MODE0 epilogue 128*EPAD
    __shared__ ushort_t smem[SMEMN];
    ushort_t* ldsB = smem;

    const int t = threadIdx.x;
    const int lane = t & 63;
    const int lane15 = lane & 15;
    const int quad = lane >> 4;
    const int wv = t >> 6;
    // XCD swizzle decode
    const int id = blockIdx.x;           // 0..511
    const int q  = id >> 3;              // mt + 2*nt + 16*(b>>3)
    const int mt = q & 1;
    const int nt = (q >> 1) & 7;
    const int b  = (id & 7) + ((q >> 4) << 3);
    const int h0 = nt * 4;
    const int p0 = nt * 128;
    const int mw0 = (wv >> 1) * 64;
    const int nw0 = (wv & 1) * 64;
    const int wbase = t & ~63;

    f32x4 acc[4][4];
    #pragma unroll
    for (int i = 0; i < 4; ++i)
        #pragma unroll
        for (int j = 0; j < 4; ++j) acc[i][j] = 0.f;

    // pre-zero (once; never overwritten): border cols w'=0,33 for all 6 rows
    if (t < 96) {
        int rix = t >> 3, j = t & 7;
        int pi = (rix >> 1) * 34 + (rix & 1) * 33;
        i32x4 z = 0;
        *(i32x4*)(&ldsB[(pi * 8 + j) * 8]) = z;
    }
    // pre-zero invalid-h interior rows (boundary blocks only; skipped by stageB)
    if (nt == 0) { i32x4 z = 0; *(i32x4*)(&ldsB[(8 + t) * 8]) = z; }                 // hh=0
    if (nt == 7) { i32x4 z = 0; *(i32x4*)(&ldsB[((5 * 34 + 1) * 8 + t) * 8]) = z; }  // hh=5

    const long xbase = (long)b * 1024 * 256;
    const long kbase = (long)b * 9 * 65536;

    auto stageB = [&](int kc) {
        #pragma unroll
        for (int hh = 0; hh < 6; ++hh) {
            int hg = h0 + hh - 1;
            if (hg < 0 || hg >= 32) continue; // block-uniform
            int ww = t >> 3;
            int pi = hh * 34 + 1 + ww;
            int jd = (t & 7) ^ (pi & 7);
            async_cp16(xin + xbase + (long)(hg * 32 + ww) * 256 + kc * 64 + jd * 8,
                       ldsB + ((hh * 34 + 1) * 8 + wbase) * 8);
        }
    };
    // direct global->VGPR A-fragment load: 8x b128, each lane 16B contiguous
    const int arow = mt * 128 + mw0 + lane15; // + mf*16
    auto issueA = [&](int kc, int pos, bf16x8* dst) {
        const ushort_t* srcA = kbank + kbase + (long)pos * 65536 + kc * 64 + quad * 8;
        #pragma unroll
        for (int kb = 0; kb < 2; ++kb)
            #pragma unroll
            for (int mf = 0; mf < 4; ++mf)
                dst[kb * 4 + mf] = *(const bf16x8*)(srcA + (long)(arow + mf * 16) * 256 + kb * 32);
    };

    bf16x8 abuf[2][8];
    stageB(0);
    issueA(0, 0, abuf[0]);
    __syncthreads(); // prologue: zero-fills + B tile + first A all landed/published

    #pragma unroll
    for (int kc = 0; kc < 4; ++kc) {
        #pragma unroll
        for (int pos = 0; pos < 9; ++pos) {
            const int it = kc * 9 + pos;
            const bool last = (it == 35);
            if (!last) {
                int nk = kc, np = pos + 1;
                if (np == 9) { np = 0; ++nk; }
                issueA(nk, np, abuf[(it + 1) & 1]);  // prefetch next A into other reg buffer
                VMCNT8();   // retires everything except the 8 just-issued: cur A + any stageB landed
            } else {
                VMCNT0();
            }
            if (pos == 0) BAR(); // publish ldsB (stageB retired by the VMCNT8 above)

            const int dh = pos / 3 - 1, dw = pos % 3 - 1;
            bf16x8 bv[2][4];
            #pragma unroll
            for (int kb = 0; kb < 2; ++kb) {
                int jk = kb * 4 + quad;
                #pragma unroll
                for (int nf = 0; nf < 4; ++nf) {
                    int n = nw0 + nf * 16 + lane15;
                    int pi = ((n >> 5) + 1 + dh) * 34 + (n & 31) + 1 + dw;
                    bv[kb][nf] = *(const bf16x8*)(&ldsB[(pi * 8 + (jk ^ (pi & 7))) * 8]);
                }
            }
            if (pos == 8 && kc < 3) {
                LGKM0();            // own ldsB reads processed
                BAR();              // all waves done reading this kc's B tile
                stageB(kc + 1);     // overwrite ldsB; lands before next vmcnt(8)+BAR
            }

            const bf16x8* af = abuf[it & 1];
            __builtin_amdgcn_s_setprio(1);
            #pragma unroll
            for (int kb = 0; kb < 2; ++kb)
                #pragma unroll
                for (int mf = 0; mf < 4; ++mf)
                    #pragma unroll
                    for (int nf = 0; nf < 4; ++nf)
                        acc[mf][nf] = __builtin_amdgcn_mfma_f32_16x16x32_bf16(af[kb * 4 + mf], bv[kb][nf], acc[mf][nf], 0, 0, 0);
            __builtin_amdgcn_s_setprio(0);
        }
    }

    // residual prefetch (MODE 1): bf16 from xt, 4 consecutive c per acc frag
    u16x4 rres[4][4];
    if (MODE == 1) {
        #pragma unroll
        for (int mf = 0; mf < 4; ++mf)
            #pragma unroll
            for (int nf = 0; nf < 4; ++nf) {
                int p = p0 + nw0 + nf * 16 + lane15;
                int cb = mt * 128 + mw0 + mf * 16 + quad * 4;
                rres[mf][nf] = *(const u16x4*)(residt + ((long)b * 1024 + p) * 256 + cb);
            }
    }

    // BN scale/shift for this lane's 16 c_out values
    float sc[4][4], sh[4][4];
    #pragma unroll
    for (int mf = 0; mf < 4; ++mf)
        #pragma unroll
        for (int i = 0; i < 4; ++i) {
            int c = mt * 128 + mw0 + mf * 16 + quad * 4 + i;
            float s = gam[c] * rsqrtf(var[c] + BN_EPS);
            sc[mf][i] = s;
            sh[mf][i] = bet[c] - mu[c] * s;
        }

    if (MODE == 0) {
        __syncthreads();
        ushort_t* ldsE = smem; // [128 p][EPAD c]
        #pragma unroll
        for (int mf = 0; mf < 4; ++mf)
            #pragma unroll
            for (int nf = 0; nf < 4; ++nf) {
                int pl = nw0 + nf * 16 + lane15;
                int cb = mw0 + mf * 16 + quad * 4;
                u16x4 pk;
                #pragma unroll
                for (int i = 0; i < 4; ++i) {
                    float v = acc[mf][nf][i] * sc[mf][i] + sh[mf][i];
                    pk[i] = f2bf(fmaxf(v, 0.f));
                }
                *(u16x4*)(&ldsE[pl * EPAD + cb]) = pk;
            }
        __syncthreads();
        ushort_t* op = (ushort_t*)outp;
        #pragma unroll
        for (int it = 0; it < 8; ++it) {
            int s = t + it * 256;
            int row = s >> 4, l16 = s & 15;
            i32x4 v = *(i32x4*)(&ldsE[row * EPAD + l16 * 8]);
            *(i32x4*)(op + ((long)b * 1024 + p0 + row) * 256 + mt * 128 + l16 * 8) = v;
        }
    } else {
        float* op = (float*)outp;
        #pragma unroll
        for (int mf = 0; mf < 4; ++mf)
            #pragma unroll
            for (int nf = 0; nf < 4; ++nf) {
                int p = p0 + nw0 + nf * 16 + lane15;
                #pragma unroll
                for (int i = 0; i < 4; ++i) {
                    int c = mt * 128 + mw0 + mf * 16 + quad * 4 + i;
                    float v = acc[mf][nf][i] * sc[mf][i] + sh[mf][i] + bf2f(rres[mf][nf][i]);
                    op[((long)b * 256 + c) * 1024 + p] = fmaxf(v, 0.f);
                }
            }
    }
}

extern "C" void kernel_launch(void* const* d_in, const int* in_sizes, int n_in,
                              void* d_out, int out_size, void* d_ws, size_t ws_size,
                              hipStream_t stream) {
    const float* x  = (const float*)d_in[0];
    const float* rw = (const float*)d_in[1];
    const float* rb = (const float*)d_in[2];
    const float* w1 = (const float*)d_in[3];
    const float* w2 = (const float*)d_in[4];
    const float* g1 = (const float*)d_in[5];
    const float* b1 = (const float*)d_in[6];
    const float* m1 = (const float*)d_in[7];
    const float* v1 = (const float*)d_in[8];
    const float* g2 = (const float*)d_in[9];
    const float* b2 = (const float*)d_in[10];
    const float* m2 = (const float*)d_in[11];
    const float* v2 = (const float*)d_in[12];

    // ws layout: r [0,1KB) | gapsum [4096, +32KB) | xt | o1 | kbuf (reused for both layers)
    const size_t GAP_OFF = 4096;
    const size_t XT_OFF  = 36864;
    const size_t O1_OFF  = XT_OFF + (size_t)16777216;
    const size_t KB_OFF  = O1_OFF + (size_t)16777216;
    const size_t NEED    = KB_OFF + (size_t)32 * 9 * 65536 * 2;
    if (ws_size < NEED) return;

    char* ws = (char*)d_ws;
    float* r       = (float*)ws;
    float* gapsum  = (float*)(ws + GAP_OFF);
    ushort_t* xt   = (ushort_t*)(ws + XT_OFF);
    ushort_t* o1   = (ushort_t*)(ws + O1_OFF);
    ushort_t* kbuf = (ushort_t*)(ws + KB_OFF);

    hipMemsetAsync(gapsum, 0, 32768, stream);
    transpose_gap_kernel<<<dim3(32, 8, 32), 256, 0, stream>>>(x, xt, gapsum);
    router_linear_kernel<<<1, 256, 0, stream>>>(gapsum, rw, rb, r);
    combine_kernel<<<dim3(512, 4), 256, 0, stream>>>(w1, r, kbuf);
    gemm_conv<0><<<512, 256, 0, stream>>>(xt, kbuf, (void*)o1, g1, b1, m1, v1, nullptr);
    combine_kernel<<<dim3(512, 4), 256, 0, stream>>>(w2, r, kbuf);
    gemm_conv<1><<<512, 256, 0, stream>>>(o1, kbuf, d_out, g2, b2, m2, v2, xt);
}

// Round 6
// 287.614 us; speedup vs baseline: 1.1233x; 1.1233x over previous
//
#include <hip/hip_runtime.h>

typedef unsigned short ushort_t;
typedef __attribute__((ext_vector_type(8))) __bf16 bf16x8;
typedef __attribute__((ext_vector_type(4))) float f32x4;
typedef __attribute__((ext_vector_type(4))) int i32x4;
typedef __attribute__((ext_vector_type(4))) unsigned short u16x4;

#define BN_EPS 1e-5f
#define EPAD 136  // epilogue [p][c] c-stride (272B row, 16B-aligned)

// counted waitcnt via inline asm (no builtin); memory clobber pins VMEM/LDS ops.
// barriers use the builtin (scheduler-aware, does NOT force a vmcnt drain).
#define BAR()    __builtin_amdgcn_s_barrier()
#define VMCNT4() asm volatile("s_waitcnt vmcnt(4)" ::: "memory")
#define VMCNT8() asm volatile("s_waitcnt vmcnt(8)" ::: "memory")
#define VMCNT0() asm volatile("s_waitcnt vmcnt(0)" ::: "memory")
#define LGKM0()  asm volatile("s_waitcnt lgkmcnt(0)" ::: "memory")

__device__ __forceinline__ ushort_t f2bf(float f) {
    union { float f; unsigned u; } v; v.f = f;
    unsigned r = v.u + 0x7FFFu + ((v.u >> 16) & 1u);
    return (ushort_t)(r >> 16);
}
__device__ __forceinline__ float bf2f(ushort_t h) {
    union { unsigned u; float f; } v; v.u = ((unsigned)h) << 16; return v.f;
}

// async 16B global->LDS copy; LDS dst is wave-uniform base (+lane*16 by HW)
__device__ __forceinline__ void async_cp16(const ushort_t* g, ushort_t* l) {
    __builtin_amdgcn_global_load_lds(
        (const __attribute__((address_space(1))) unsigned int*)g,
        (__attribute__((address_space(3))) unsigned int*)l, 16, 0, 0);
}

// ---------------- transpose+cast+GAP: x[b][c][p] f32 -> xt[b][p][c] bf16, partial GAP sums ----------------
__global__ void transpose_gap_kernel(const float* __restrict__ x, ushort_t* __restrict__ xt,
                                     float* __restrict__ gapsum) {
    __shared__ float tile[32][33];
    int b = blockIdx.z, c0 = blockIdx.y * 32, p0 = blockIdx.x * 32;
    int tx = threadIdx.x & 31, ty = threadIdx.x >> 5; // ty 0..7
    float ps[4];
    #pragma unroll
    for (int i = 0; i < 4; ++i) {
        int c = ty + i * 8;
        float v = x[((long)b * 256 + c0 + c) * 1024 + p0 + tx];
        tile[c][tx] = v;
        ps[i] = v;
    }
    #pragma unroll
    for (int off = 16; off; off >>= 1)
        #pragma unroll
        for (int i = 0; i < 4; ++i) ps[i] += __shfl_down(ps[i], off, 32);
    if (tx == 0)
        #pragma unroll
        for (int i = 0; i < 4; ++i) atomicAdd(&gapsum[b * 256 + c0 + ty + i * 8], ps[i]);
    __syncthreads();
    #pragma unroll
    for (int i = 0; i < 4; ++i) {
        int p = ty + i * 8;
        xt[((long)b * 1024 + p0 + p) * 256 + c0 + tx] = f2bf(tile[tx][p]);
    }
}

// ---------------- router linear: r = sigmoid(gap/1024 @ rw^T + rb) ----------------
__global__ void router_linear_kernel(const float* __restrict__ gapsum, const float* __restrict__ rw,
                                     const float* __restrict__ rb, float* __restrict__ r) {
    int t = threadIdx.x, b = t >> 3, e = t & 7;
    float s = 0.f;
    for (int c = 0; c < 256; ++c) s += gapsum[b * 256 + c] * rw[e * 256 + c];
    r[t] = 1.f / (1.f + expf(-(s * (1.f / 1024.f) + rb[e])));
}

// ---------------- combine: ko[b][pos][g] = sum_e r[b,e]*w[e][g][pos], bf16 ----------------
// LDS-staged: block stages a 128-g chunk of w (all 8 e x 9 p = 36.9KB f32) with
// fully-coalesced float4 loads, then each thread owns one g (contiguous 9-float LDS
// run, stride-9-dword = conflict-free), 72 FMA + 9 coalesced 2B stores per b.
__global__ __launch_bounds__(256, 4) void combine_kernel(const float* __restrict__ w,
                                                         const float* __restrict__ r,
                                                         ushort_t* __restrict__ ko) {
    __shared__ float wl[9216]; // [e][128 g * 9 p] raster, 36864 B
    const int t = threadIdx.x;
    const int g0 = blockIdx.x * 128;
    const int b0 = blockIdx.y * 8;

    // stage: 2304 float4 (9216 floats), 9 float4 per thread, coalesced
    #pragma unroll
    for (int it = 0; it < 9; ++it) {
        int lin = it * 256 + t;            // float4 index in chunk
        int e = lin / 288, rem = lin - e * 288;  // 288 float4 per e-section
        f32x4 v = *(const f32x4*)(w + (long)e * 589824 + (long)g0 * 9 + rem * 4);
        *(f32x4*)(&wl[lin * 4]) = v;
    }
    __syncthreads();

    const int g = t & 127;       // owned g within chunk
    const int half = t >> 7;     // 0/1: which 4 of the 8 b's
    float wv[8][9];
    #pragma unroll
    for (int e = 0; e < 8; ++e)
        #pragma unroll
        for (int p = 0; p < 9; ++p)
            wv[e][p] = wl[e * 1152 + g * 9 + p];

    #pragma unroll
    for (int j = 0; j < 4; ++j) {
        int b = b0 + half * 4 + j;
        float rv[8];
        #pragma unroll
        for (int e = 0; e < 8; ++e) rv[e] = r[b * 8 + e];
        #pragma unroll
        for (int p = 0; p < 9; ++p) {
            float s = 0.f;
            #pragma unroll
            for (int e = 0; e < 8; ++e) s += rv[e] * wv[e][p];
            ko[((long)(b * 9 + p)) * 65536 + g0 + g] = f2bf(s);
        }
    }
}

// ---------------- implicit-GEMM conv 3x3 (pad 1), per-sample weights ----------------
// Grid: 512 linear blocks, XCD-swizzled: id%8 = b%8 so all 16 (nt,mt) siblings of a
// sample land on one XCD => weight/x L2 reuse.
// APATH 0 (control, round-3 verified): A staged via global_load_lds into XOR-swizzled
//   ldsA double buffer; counted VMCNT4 2-barrier-per-iter schedule.
// APATH 1 (experiment): A loaded DIRECT global->VGPR (16B/lane fragments, register
//   double buffer abufA/abufB), ROLLED 18x2-phase loop (#pragma unroll 1 — round-5's
//   full unroll blew I$: all-pipes-idle signature). Halves LDS-pipe traffic/iter.
//   vmcnt(8) at each wait retires {cur A (8) + any stageB (<=6)}, leaving only the
//   just-issued prefetch in flight. Barriers only at pos==0 (publish B) and pos==8
//   (B-tile reuse fence) — block-uniform runtime conds.
// LDS ldsB: halo [6][34] rows x 8 k-chunks; slot(pi,j) = pi*8 + (j ^ (pi&7)) (16B units)
// MODE 0: out = bf16 relu(bn(conv)) [b][p][c];  MODE 1: out = f32 relu(bn(conv)+resid) [b][c][p]
template <int MODE, int APATH>
__global__ __launch_bounds__(256, 2) void gemm_conv(
    const ushort_t* __restrict__ xin,   // [B][1024][256] bf16
    const ushort_t* __restrict__ kbank, // [B][9][256][256] bf16
    void* __restrict__ outp,
    const float* __restrict__ gam, const float* __restrict__ bet,
    const float* __restrict__ mu, const float* __restrict__ var,
    const ushort_t* __restrict__ residt) { // [B][1024][256] bf16 (MODE 1 only)
    constexpr int SMEMN = (APATH == 0) ? 29440 : ((MODE == 0) ? 17408 : 13056);
    __shared__ ushort_t smem[SMEMN];
    ushort_t* ldsB = smem;

    const int t = threadIdx.x;
    const int lane = t & 63;
    const int lane15 = lane & 15;
    const int quad = lane >> 4;
    const int wv = t >> 6;
    // XCD swizzle decode
    const int id = blockIdx.x;           // 0..511
    const int q  = id >> 3;              // mt + 2*nt + 16*(b>>3)
    const int mt = q & 1;
    const int nt = (q >> 1) & 7;
    const int b  = (id & 7) + ((q >> 4) << 3);
    const int h0 = nt * 4;
    const int p0 = nt * 128;
    const int mw0 = (wv >> 1) * 64;
    const int nw0 = (wv & 1) * 64;
    const int wbase = t & ~63;

    f32x4 acc[4][4];
    #pragma unroll
    for (int i = 0; i < 4; ++i)
        #pragma unroll
        for (int j = 0; j < 4; ++j) acc[i][j] = 0.f;

    // pre-zero (once; never overwritten): border cols w'=0,33 for all 6 rows
    if (t < 96) {
        int rix = t >> 3, j = t & 7;
        int pi = (rix >> 1) * 34 + (rix & 1) * 33;
        i32x4 z = 0;
        *(i32x4*)(&ldsB[(pi * 8 + j) * 8]) = z;
    }
    // pre-zero invalid-h interior rows (boundary blocks only; skipped by stageB)
    if (nt == 0) { i32x4 z = 0; *(i32x4*)(&ldsB[(8 + t) * 8]) = z; }                 // hh=0
    if (nt == 7) { i32x4 z = 0; *(i32x4*)(&ldsB[((5 * 34 + 1) * 8 + t) * 8]) = z; }  // hh=5

    const long xbase = (long)b * 1024 * 256;
    const long kbase = (long)b * 9 * 65536;

    auto stageB = [&](int kc) {
        #pragma unroll
        for (int hh = 0; hh < 6; ++hh) {
            int hg = h0 + hh - 1;
            if (hg < 0 || hg >= 32) continue; // block-uniform
            int ww = t >> 3;
            int pi = hh * 34 + 1 + ww;
            int jd = (t & 7) ^ (pi & 7);
            async_cp16(xin + xbase + (long)(hg * 32 + ww) * 256 + kc * 64 + jd * 8,
                       ldsB + ((hh * 34 + 1) * 8 + wbase) * 8);
        }
    };

    if constexpr (APATH == 0) {
        ushort_t* ldsA = smem + 13056;
        auto stageA = [&](int kc, int pos, int buf) {
            const ushort_t* srcA = kbank + kbase + (long)pos * 65536 + (long)mt * 32768 + kc * 64;
            ushort_t* base = ldsA + buf * 8192;
            #pragma unroll
            for (int it = 0; it < 4; ++it) {
                int s = it * 256 + t;
                int row = s >> 3;
                int k8 = (s & 7) ^ (row & 7);
                async_cp16(srcA + (long)row * 256 + k8 * 8, base + (it * 256 + wbase) * 8);
            }
        };

        stageB(0);
        stageA(0, 0, 0);
        __syncthreads(); // prologue: zero-fills + B tile + first A landed/published

        int par = 0;
        for (int kc = 0; kc < 4; ++kc) {
            for (int pos = 0; pos < 9; ++pos) {
                const bool last = (kc == 3 && pos == 8);
                if (!last) {
                    int nk = kc, np = pos + 1;
                    if (np == 9) { np = 0; ++nk; }
                    stageA(nk, np, par ^ 1);
                    VMCNT4();
                } else {
                    VMCNT0();
                }
                BAR();

                const int dh = pos / 3 - 1, dw = pos % 3 - 1;
                const ushort_t* ab = ldsA + par * 8192;
                bf16x8 af[2][4], bfr[2][4];
                #pragma unroll
                for (int kb = 0; kb < 2; ++kb) {
                    int jk = kb * 4 + quad;
                    #pragma unroll
                    for (int mf = 0; mf < 4; ++mf) {
                        int row = mw0 + mf * 16 + lane15;
                        af[kb][mf] = *(const bf16x8*)(ab + (row * 8 + (jk ^ (row & 7))) * 8);
                    }
                    #pragma unroll
                    for (int nf = 0; nf < 4; ++nf) {
                        int n = nw0 + nf * 16 + lane15;
                        int pi = ((n >> 5) + 1 + dh) * 34 + (n & 31) + 1 + dw;
                        bfr[kb][nf] = *(const bf16x8*)(&ldsB[(pi * 8 + (jk ^ (pi & 7))) * 8]);
                    }
                }
                LGKM0();
                BAR();

                if (pos == 8 && kc < 3) stageB(kc + 1);

                __builtin_amdgcn_s_setprio(1);
                #pragma unroll
                for (int kb = 0; kb < 2; ++kb)
                    #pragma unroll
                    for (int mf = 0; mf < 4; ++mf)
                        #pragma unroll
                        for (int nf = 0; nf < 4; ++nf)
                            acc[mf][nf] = __builtin_amdgcn_mfma_f32_16x16x32_bf16(af[kb][mf], bfr[kb][nf], acc[mf][nf], 0, 0, 0);
                __builtin_amdgcn_s_setprio(0);
                par ^= 1;
            }
        }
    } else {
        // ---- APATH 1: direct global->VGPR A, rolled 18x2-phase loop ----
        const int arow = mt * 128 + mw0 + lane15;     // + mf*16
        const long abase = kbase + (long)arow * 256 + quad * 8;
        bf16x8 abufA[8], abufB[8];

#define ISSUEA(nk, np, dst) {                                                     \
        const ushort_t* sA = kbank + abase + ((np) * 65536 + (nk) * 64);          \
        _Pragma("unroll")                                                         \
        for (int kb = 0; kb < 2; ++kb)                                            \
            _Pragma("unroll")                                                     \
            for (int mf = 0; mf < 4; ++mf)                                        \
                dst[kb * 4 + mf] = *(const bf16x8*)(sA + (long)(mf * 16) * 256 + kb * 32); }

#define STEP(cur, nxt) {                                                          \
        const int itx = kc * 9 + pos;                                             \
        if (itx != 35) {                                                          \
            int np = pos + 1, nk = kc;                                            \
            if (np == 9) { np = 0; ++nk; }                                        \
            ISSUEA(nk, np, nxt);                                                  \
            VMCNT8();                                                             \
        } else { VMCNT0(); }                                                      \
        if (pos == 0) BAR();                                                      \
        const int dh = pos / 3 - 1, dw = pos % 3 - 1;                             \
        bf16x8 bv[2][4];                                                          \
        _Pragma("unroll")                                                         \
        for (int kb = 0; kb < 2; ++kb) {                                          \
            int jk = kb * 4 + quad;                                               \
            _Pragma("unroll")                                                     \
            for (int nf = 0; nf < 4; ++nf) {                                      \
                int n = nw0 + nf * 16 + lane15;                                   \
                int pi = ((n >> 5) + 1 + dh) * 34 + (n & 31) + 1 + dw;            \
                bv[kb][nf] = *(const bf16x8*)(&ldsB[(pi * 8 + (jk ^ (pi & 7))) * 8]); \
            } }                                                                   \
        if (pos == 8 && kc < 3) { LGKM0(); BAR(); stageB(kc + 1); }               \
        __builtin_amdgcn_s_setprio(1);                                            \
        _Pragma("unroll")                                                         \
        for (int kb = 0; kb < 2; ++kb)                                            \
            _Pragma("unroll")                                                     \
            for (int mf = 0; mf < 4; ++mf)                                        \
                _Pragma("unroll")                                                 \
                for (int nf = 0; nf < 4; ++nf)                                    \
                    acc[mf][nf] = __builtin_amdgcn_mfma_f32_16x16x32_bf16(cur[kb * 4 + mf], bv[kb][nf], acc[mf][nf], 0, 0, 0); \
        __builtin_amdgcn_s_setprio(0);                                            \
        ++pos; if (pos == 9) { pos = 0; ++kc; }                                   \
}

        stageB(0);
        ISSUEA(0, 0, abufA);
        __syncthreads(); // prologue drain: zero-fills + B tile + first A

        int kc = 0, pos = 0;
        #pragma unroll 1
        for (int d = 0; d < 18; ++d) {
            STEP(abufA, abufB)
            STEP(abufB, abufA)
        }
#undef STEP
#undef ISSUEA
    }

    // residual prefetch (MODE 1): bf16 from xt, 4 consecutive c per acc frag
    u16x4 rres[4][4];
    if (MODE == 1) {
        #pragma unroll
        for (int mf = 0; mf < 4; ++mf)
            #pragma unroll
            for (int nf = 0; nf < 4; ++nf) {
                int p = p0 + nw0 + nf * 16 + lane15;
                int cb = mt * 128 + mw0 + mf * 16 + quad * 4;
                rres[mf][nf] = *(const u16x4*)(residt + ((long)b * 1024 + p) * 256 + cb);
            }
    }

    // BN scale/shift for this lane's 16 c_out values
    float sc[4][4], sh[4][4];
    #pragma unroll
    for (int mf = 0; mf < 4; ++mf)
        #pragma unroll
        for (int i = 0; i < 4; ++i) {
            int c = mt * 128 + mw0 + mf * 16 + quad * 4 + i;
            float s = gam[c] * rsqrtf(var[c] + BN_EPS);
            sc[mf][i] = s;
            sh[mf][i] = bet[c] - mu[c] * s;
        }

    if (MODE == 0) {
        __syncthreads();
        ushort_t* ldsE = smem; // [128 p][EPAD c]
        #pragma unroll
        for (int mf = 0; mf < 4; ++mf)
            #pragma unroll
            for (int nf = 0; nf < 4; ++nf) {
                int pl = nw0 + nf * 16 + lane15;
                int cb = mw0 + mf * 16 + quad * 4;
                u16x4 pk;
                #pragma unroll
                for (int i = 0; i < 4; ++i) {
                    float v = acc[mf][nf][i] * sc[mf][i] + sh[mf][i];
                    pk[i] = f2bf(fmaxf(v, 0.f));
                }
                *(u16x4*)(&ldsE[pl * EPAD + cb]) = pk;
            }
        __syncthreads();
        ushort_t* op = (ushort_t*)outp;
        #pragma unroll
        for (int it = 0; it < 8; ++it) {
            int s = t + it * 256;
            int row = s >> 4, l16 = s & 15;
            i32x4 v = *(i32x4*)(&ldsE[row * EPAD + l16 * 8]);
            *(i32x4*)(op + ((long)b * 1024 + p0 + row) * 256 + mt * 128 + l16 * 8) = v;
        }
    } else {
        float* op = (float*)outp;
        #pragma unroll
        for (int mf = 0; mf < 4; ++mf)
            #pragma unroll
            for (int nf = 0; nf < 4; ++nf) {
                int p = p0 + nw0 + nf * 16 + lane15;
                #pragma unroll
                for (int i = 0; i < 4; ++i) {
                    int c = mt * 128 + mw0 + mf * 16 + quad * 4 + i;
                    float v = acc[mf][nf][i] * sc[mf][i] + sh[mf][i] + bf2f(rres[mf][nf][i]);
                    op[((long)b * 256 + c) * 1024 + p] = fmaxf(v, 0.f);
                }
            }
    }
}

extern "C" void kernel_launch(void* const* d_in, const int* in_sizes, int n_in,
                              void* d_out, int out_size, void* d_ws, size_t ws_size,
                              hipStream_t stream) {
    const float* x  = (const float*)d_in[0];
    const float* rw = (const float*)d_in[1];
    const float* rb = (const float*)d_in[2];
    const float* w1 = (const float*)d_in[3];
    const float* w2 = (const float*)d_in[4];
    const float* g1 = (const float*)d_in[5];
    const float* b1 = (const float*)d_in[6];
    const float* m1 = (const float*)d_in[7];
    const float* v1 = (const float*)d_in[8];
    const float* g2 = (const float*)d_in[9];
    const float* b2 = (const float*)d_in[10];
    const float* m2 = (const float*)d_in[11];
    const float* v2 = (const float*)d_in[12];

    // ws layout: r [0,1KB) | gapsum [4096, +32KB) | xt | o1 | kbuf (reused for both layers)
    const size_t GAP_OFF = 4096;
    const size_t XT_OFF  = 36864;
    const size_t O1_OFF  = XT_OFF + (size_t)16777216;
    const size_t KB_OFF  = O1_OFF + (size_t)16777216;
    const size_t NEED    = KB_OFF + (size_t)32 * 9 * 65536 * 2;
    if (ws_size < NEED) return;

    char* ws = (char*)d_ws;
    float* r       = (float*)ws;
    float* gapsum  = (float*)(ws + GAP_OFF);
    ushort_t* xt   = (ushort_t*)(ws + XT_OFF);
    ushort_t* o1   = (ushort_t*)(ws + O1_OFF);
    ushort_t* kbuf = (ushort_t*)(ws + KB_OFF);

    hipMemsetAsync(gapsum, 0, 32768, stream);
    transpose_gap_kernel<<<dim3(32, 8, 32), 256, 0, stream>>>(x, xt, gapsum);
    router_linear_kernel<<<1, 256, 0, stream>>>(gapsum, rw, rb, r);
    combine_kernel<<<dim3(512, 4), 256, 0, stream>>>(w1, r, kbuf);
    gemm_conv<0, 1><<<512, 256, 0, stream>>>(xt, kbuf, (void*)o1, g1, b1, m1, v1, nullptr);
    combine_kernel<<<dim3(512, 4), 256, 0, stream>>>(w2, r, kbuf);
    gemm_conv<1, 0><<<512, 256, 0, stream>>>(o1, kbuf, d_out, g2, b2, m2, v2, xt);
}

// Round 8
// 239.843 us; speedup vs baseline: 1.3470x; 1.1992x over previous
//
#include <hip/hip_runtime.h>

typedef unsigned short ushort_t;
typedef __attribute__((ext_vector_type(8))) __bf16 bf16x8;
typedef __attribute__((ext_vector_type(4))) float f32x4;
typedef __attribute__((ext_vector_type(4))) int i32x4;
typedef __attribute__((ext_vector_type(4))) unsigned short u16x4;

#define BN_EPS 1e-5f
#define EPAD 136  // epilogue [p][c] c-stride (272B row, 16B-aligned)

// counted waitcnt via inline asm (no builtin); memory clobber pins VMEM/LDS ops.
// barriers use the builtin (scheduler-aware, does NOT force a vmcnt drain).
#define BAR()    __builtin_amdgcn_s_barrier()
#define VMCNT4() asm volatile("s_waitcnt vmcnt(4)" ::: "memory")
#define VMCNT0() asm volatile("s_waitcnt vmcnt(0)" ::: "memory")
#define LGKM0()  asm volatile("s_waitcnt lgkmcnt(0)" ::: "memory")

__device__ __forceinline__ ushort_t f2bf(float f) {
    union { float f; unsigned u; } v; v.f = f;
    unsigned r = v.u + 0x7FFFu + ((v.u >> 16) & 1u);
    return (ushort_t)(r >> 16);
}
__device__ __forceinline__ float bf2f(ushort_t h) {
    union { unsigned u; float f; } v; v.u = ((unsigned)h) << 16; return v.f;
}

// async 16B global->LDS copy; LDS dst is wave-uniform base (+lane*16 by HW)
__device__ __forceinline__ void async_cp16(const ushort_t* g, ushort_t* l) {
    __builtin_amdgcn_global_load_lds(
        (const __attribute__((address_space(1))) unsigned int*)g,
        (__attribute__((address_space(3))) unsigned int*)l, 16, 0, 0);
}

// ---------------- transpose+cast+GAP: x[b][c][p] f32 -> xt[b][p][c] bf16, partial GAP sums ----------------
// Vectorized: float4 loads (16B/lane), u16x4 stores (8B/lane). GAP via 8-lane shfl reduce.
__global__ void transpose_gap_kernel(const float* __restrict__ x, ushort_t* __restrict__ xt,
                                     float* __restrict__ gapsum) {
    __shared__ float tile[32][33]; // [c][p], +1 pad
    int b = blockIdx.z, c0 = blockIdx.y * 32, p0 = blockIdx.x * 32;
    int t = threadIdx.x;
    int c = t >> 3, q = t & 7;         // c 0..31, q = p-quad 0..7
    f32x4 v = *(const f32x4*)(x + ((long)b * 256 + c0 + c) * 1024 + p0 + q * 4);
    tile[c][q * 4 + 0] = v[0];
    tile[c][q * 4 + 1] = v[1];
    tile[c][q * 4 + 2] = v[2];
    tile[c][q * 4 + 3] = v[3];
    float ps = v[0] + v[1] + v[2] + v[3];
    ps += __shfl_down(ps, 4, 8);
    ps += __shfl_down(ps, 2, 8);
    ps += __shfl_down(ps, 1, 8);
    if (q == 0) atomicAdd(&gapsum[b * 256 + c0 + c], ps);
    __syncthreads();
    int p = t >> 3, coff = (t & 7) * 4; // p 0..31, 4 consecutive c per lane
    u16x4 pk;
    #pragma unroll
    for (int i = 0; i < 4; ++i) pk[i] = f2bf(tile[coff + i][p]);
    *(u16x4*)(xt + ((long)b * 1024 + p0 + p) * 256 + c0 + coff) = pk;
}

// ---------------- router linear: r = sigmoid(gap/1024 @ rw^T + rb) ----------------
__global__ void router_linear_kernel(const float* __restrict__ gapsum, const float* __restrict__ rw,
                                     const float* __restrict__ rb, float* __restrict__ r) {
    int t = threadIdx.x, b = t >> 3, e = t & 7;
    float s = 0.f;
    for (int c = 0; c < 256; ++c) s += gapsum[b * 256 + c] * rw[e * 256 + c];
    r[t] = 1.f / (1.f + expf(-(s * (1.f / 1024.f) + rb[e])));
}

// ---------------- combine: ko[b][pos][g] = sum_e r[b,e]*w[e][g][pos], bf16 ----------------
// Stage-in: 128-g chunk of w (8e x 9p = 36.9KB f32) via coalesced float4 loads.
// Compute: thread owns one g (contiguous 9-float LDS runs, conflict-free), 72 w in VGPRs.
// Stage-out: results written bf16 to LDS (aliasing wl after wv reg-loads + barrier),
// then 1152 x 16B fully-coalesced global stores — replaces 2B/lane scalar stores.
__global__ __launch_bounds__(256, 4) void combine_kernel(const float* __restrict__ w,
                                                         const float* __restrict__ r,
                                                         ushort_t* __restrict__ ko) {
    __shared__ float wl[9216]; // 36864 B; reused as outb (18432 B) after wv loads
    ushort_t* outb = (ushort_t*)wl;
    const int t = threadIdx.x;
    const int g0 = blockIdx.x * 128;
    const int b0 = blockIdx.y * 8;

    // stage-in: 2304 float4, 9 per thread, coalesced ((g,p) raster IS w's layout)
    #pragma unroll
    for (int it = 0; it < 9; ++it) {
        int lin = it * 256 + t;
        int e = lin / 288, rem = lin - e * 288;
        f32x4 v = *(const f32x4*)(w + (long)e * 589824 + (long)g0 * 9 + rem * 4);
        *(f32x4*)(&wl[lin * 4]) = v;
    }
    __syncthreads();

    const int g = t & 127;
    const int half = t >> 7;
    float wv[8][9];
    #pragma unroll
    for (int e = 0; e < 8; ++e)
        #pragma unroll
        for (int p = 0; p < 9; ++p)
            wv[e][p] = wl[e * 1152 + g * 9 + p];
    __syncthreads(); // all wl reads done -> safe to alias as outb

    #pragma unroll
    for (int j = 0; j < 4; ++j) {
        int b8 = half * 4 + j;
        float rv[8];
        #pragma unroll
        for (int e = 0; e < 8; ++e) rv[e] = r[(b0 + b8) * 8 + e];
        #pragma unroll
        for (int p = 0; p < 9; ++p) {
            float s = 0.f;
            #pragma unroll
            for (int e = 0; e < 8; ++e) s += rv[e] * wv[e][p];
            outb[(b8 * 9 + p) * 128 + g] = f2bf(s); // 2B LDS scatter: 2-way, free
        }
    }
    __syncthreads();

    // stage-out: 8b x 9p x 128g bf16 = 1152 16B chunks, coalesced
    #pragma unroll
    for (int it = 0; it < 5; ++it) {
        int idx = it * 256 + t;
        if (idx < 1152) {
            int row = idx >> 4, off = idx & 15; // row = b8*9+p
            int b8 = row / 9, p = row - b8 * 9;
            i32x4 v = *(i32x4*)(&outb[row * 128 + off * 8]);
            *(i32x4*)(ko + ((long)((b0 + b8) * 9 + p)) * 65536 + g0 + off * 8) = v;
        }
    }
}

// ---------------- implicit-GEMM conv 3x3 (pad 1), per-sample weights ----------------
// Round-3-verified structure (41.6-43 us): A staged via global_load_lds into XOR-swizzled
// ldsA double buffer; counted-vmcnt 2-barrier-per-iter schedule. Direct-A (round 6) was
// 2x WORSE: per-lane fragment gather = 16 scattered 64B segments per load instr ->
// transaction-bound. Grid: 512 blocks, XCD-swizzled (id%8 = b%8 -> L2 reuse of kbank/x).
// LDS (16B chunks, XOR-swizzled, written only by global_load_lds):
//   ldsB: halo [6][34] rows x 8 k-chunks; slot(pi,j) = pi*8 + (j ^ (pi&7))
//   ldsA: 2 x (128 rows x 8 k-chunks); slot(row,j) = row*8 + (j ^ (row&7))
// MODE 0: out = bf16 relu(bn(conv)) [b][p][c];  MODE 1: out = f32 relu(bn(conv)+resid) [b][c][p]
template <int MODE>
__global__ __launch_bounds__(256, 2) void gemm_conv(
    const ushort_t* __restrict__ xin,   // [B][1024][256] bf16
    const ushort_t* __restrict__ kbank, // [B][9][256][256] bf16
    void* __restrict__ outp,
    const float* __restrict__ gam, const float* __restrict__ bet,
    const float* __restrict__ mu, const float* __restrict__ var,
    const ushort_t* __restrict__ residt) { // [B][1024][256] bf16 (MODE 1 only)
    __shared__ ushort_t smem[29440]; // ldsB: [0,13056) ; ldsA: [13056, 13056+16384)
    ushort_t* ldsB = smem;
    ushort_t* ldsA = smem + 13056;

    const int t = threadIdx.x;
    const int lane = t & 63;
    const int lane15 = lane & 15;
    const int quad = lane >> 4;
    const int wv = t >> 6;
    // XCD swizzle decode
    const int id = blockIdx.x;           // 0..511
    const int q  = id >> 3;              // mt + 2*nt + 16*(b>>3)
    const int mt = q & 1;
    const int nt = (q >> 1) & 7;
    const int b  = (id & 7) + ((q >> 4) << 3);
    const int h0 = nt * 4;
    const int p0 = nt * 128;
    const int mw0 = (wv >> 1) * 64;
    const int nw0 = (wv & 1) * 64;
    const int wbase = t & ~63;

    f32x4 acc[4][4];
    #pragma unroll
    for (int i = 0; i < 4; ++i)
        #pragma unroll
        for (int j = 0; j < 4; ++j) acc[i][j] = 0.f;

    // pre-zero (once; never overwritten): border cols w'=0,33 for all 6 rows
    if (t < 96) {
        int rix = t >> 3, j = t & 7;
        int pi = (rix >> 1) * 34 + (rix & 1) * 33;
        i32x4 z = 0;
        *(i32x4*)(&ldsB[(pi * 8 + j) * 8]) = z;
    }
    // pre-zero invalid-h interior rows (boundary blocks only; skipped by stageB)
    if (nt == 0) { i32x4 z = 0; *(i32x4*)(&ldsB[(8 + t) * 8]) = z; }                 // hh=0
    if (nt == 7) { i32x4 z = 0; *(i32x4*)(&ldsB[((5 * 34 + 1) * 8 + t) * 8]) = z; }  // hh=5

    const long xbase = (long)b * 1024 * 256;
    const long kbase = (long)b * 9 * 65536;

    auto stageB = [&](int kc) {
        #pragma unroll
        for (int hh = 0; hh < 6; ++hh) {
            int hg = h0 + hh - 1;
            if (hg < 0 || hg >= 32) continue; // block-uniform
            int ww = t >> 3;
            int pi = hh * 34 + 1 + ww;
            int jd = (t & 7) ^ (pi & 7);
            async_cp16(xin + xbase + (long)(hg * 32 + ww) * 256 + kc * 64 + jd * 8,
                       ldsB + ((hh * 34 + 1) * 8 + wbase) * 8);
        }
    };
    auto stageA = [&](int kc, int pos, int buf) {
        const ushort_t* srcA = kbank + kbase + (long)pos * 65536 + (long)mt * 32768 + kc * 64;
        ushort_t* base = ldsA + buf * 8192;
        #pragma unroll
        for (int it = 0; it < 4; ++it) {
            int s = it * 256 + t;
            int row = s >> 3;
            int k8 = (s & 7) ^ (row & 7);
            async_cp16(srcA + (long)row * 256 + k8 * 8, base + (it * 256 + wbase) * 8);
        }
    };

    stageB(0);
    stageA(0, 0, 0);
    __syncthreads(); // prologue: zero-fills + B tile + first A landed/published

    int par = 0;
    for (int kc = 0; kc < 4; ++kc) {
        for (int pos = 0; pos < 9; ++pos) {
            const bool last = (kc == 3 && pos == 8);
            if (!last) {
                int nk = kc, np = pos + 1;
                if (np == 9) { np = 0; ++nk; }
                stageA(nk, np, par ^ 1);   // 4 loads into buf[par^1]
                VMCNT4();                   // all-but-newest-4: buf[par] (+B at kc edge) landed
            } else {
                VMCNT0();
            }
            BAR();                          // bar_pub: stage data visible

            const int dh = pos / 3 - 1, dw = pos % 3 - 1;
            const ushort_t* ab = ldsA + par * 8192;
            bf16x8 af[2][4], bfr[2][4];
            #pragma unroll
            for (int kb = 0; kb < 2; ++kb) {
                int jk = kb * 4 + quad;
                #pragma unroll
                for (int mf = 0; mf < 4; ++mf) {
                    int row = mw0 + mf * 16 + lane15;
                    af[kb][mf] = *(const bf16x8*)(ab + (row * 8 + (jk ^ (row & 7))) * 8);
                }
                #pragma unroll
                for (int nf = 0; nf < 4; ++nf) {
                    int n = nw0 + nf * 16 + lane15;
                    int pi = ((n >> 5) + 1 + dh) * 34 + (n & 31) + 1 + dw;
                    bfr[kb][nf] = *(const bf16x8*)(&ldsB[(pi * 8 + (jk ^ (pi & 7))) * 8]);
                }
            }
            LGKM0();                        // own ds_reads retired
            BAR();                          // bar_rd: all waves done reading buf[par]/ldsB

            if (pos == 8 && kc < 3) stageB(kc + 1); // safe after bar_rd; lands by next vmcnt+bar

            __builtin_amdgcn_s_setprio(1);
            #pragma unroll
            for (int kb = 0; kb < 2; ++kb)
                #pragma unroll
                for (int mf = 0; mf < 4; ++mf)
                    #pragma unroll
                    for (int nf = 0; nf < 4; ++nf)
                        acc[mf][nf] = __builtin_amdgcn_mfma_f32_16x16x32_bf16(af[kb][mf], bfr[kb][nf], acc[mf][nf], 0, 0, 0);
            __builtin_amdgcn_s_setprio(0);
            par ^= 1;
        }
    }

    // residual prefetch (MODE 1): bf16 from xt, 4 consecutive c per acc frag
    u16x4 rres[4][4];
    if (MODE == 1) {
        #pragma unroll
        for (int mf = 0; mf < 4; ++mf)
            #pragma unroll
            for (int nf = 0; nf < 4; ++nf) {
                int p = p0 + nw0 + nf * 16 + lane15;
                int cb = mt * 128 + mw0 + mf * 16 + quad * 4;
                rres[mf][nf] = *(const u16x4*)(residt + ((long)b * 1024 + p) * 256 + cb);
            }
    }

    // BN scale/shift for this lane's 16 c_out values
    float sc[4][4], sh[4][4];
    #pragma unroll
    for (int mf = 0; mf < 4; ++mf)
        #pragma unroll
        for (int i = 0; i < 4; ++i) {
            int c = mt * 128 + mw0 + mf * 16 + quad * 4 + i;
            float s = gam[c] * rsqrtf(var[c] + BN_EPS);
            sc[mf][i] = s;
            sh[mf][i] = bet[c] - mu[c] * s;
        }

    if (MODE == 0) {
        __syncthreads();
        ushort_t* ldsE = smem; // [128 p][EPAD c]
        #pragma unroll
        for (int mf = 0; mf < 4; ++mf)
            #pragma unroll
            for (int nf = 0; nf < 4; ++nf) {
                int pl = nw0 + nf * 16 + lane15;
                int cb = mw0 + mf * 16 + quad * 4;
                u16x4 pk;
                #pragma unroll
                for (int i = 0; i < 4; ++i) {
                    float v = acc[mf][nf][i] * sc[mf][i] + sh[mf][i];
                    pk[i] = f2bf(fmaxf(v, 0.f));
                }
                *(u16x4*)(&ldsE[pl * EPAD + cb]) = pk;
            }
        __syncthreads();
        ushort_t* op = (ushort_t*)outp;
        #pragma unroll
        for (int it = 0; it < 8; ++it) {
            int s = t + it * 256;
            int row = s >> 4, l16 = s & 15;
            i32x4 v = *(i32x4*)(&ldsE[row * EPAD + l16 * 8]);
            *(i32x4*)(op + ((long)b * 1024 + p0 + row) * 256 + mt * 128 + l16 * 8) = v;
        }
    } else {
        float* op = (float*)outp;
        #pragma unroll
        for (int mf = 0; mf < 4; ++mf)
            #pragma unroll
            for (int nf = 0; nf < 4; ++nf) {
                int p = p0 + nw0 + nf * 16 + lane15;
                #pragma unroll
                for (int i = 0; i < 4; ++i) {
                    int c = mt * 128 + mw0 + mf * 16 + quad * 4 + i;
                    float v = acc[mf][nf][i] * sc[mf][i] + sh[mf][i] + bf2f(rres[mf][nf][i]);
                    op[((long)b * 256 + c) * 1024 + p] = fmaxf(v, 0.f);
                }
            }
    }
}

extern "C" void kernel_launch(void* const* d_in, const int* in_sizes, int n_in,
                              void* d_out, int out_size, void* d_ws, size_t ws_size,
                              hipStream_t stream) {
    const float* x  = (const float*)d_in[0];
    const float* rw = (const float*)d_in[1];
    const float* rb = (const float*)d_in[2];
    const float* w1 = (const float*)d_in[3];
    const float* w2 = (const float*)d_in[4];
    const float* g1 = (const float*)d_in[5];
    const float* b1 = (const float*)d_in[6];
    const float* m1 = (const float*)d_in[7];
    const float* v1 = (const float*)d_in[8];
    const float* g2 = (const float*)d_in[9];
    const float* b2 = (const float*)d_in[10];
    const float* m2 = (const float*)d_in[11];
    const float* v2 = (const float*)d_in[12];

    // ws layout: r [0,1KB) | gapsum [4096, +32KB) | xt | o1 | kbuf (reused for both layers)
    const size_t GAP_OFF = 4096;
    const size_t XT_OFF  = 36864;
    const size_t O1_OFF  = XT_OFF + (size_t)16777216;
    const size_t KB_OFF  = O1_OFF + (size_t)16777216;
    const size_t NEED    = KB_OFF + (size_t)32 * 9 * 65536 * 2;
    if (ws_size < NEED) return;

    char* ws = (char*)d_ws;
    float* r       = (float*)ws;
    float* gapsum  = (float*)(ws + GAP_OFF);
    ushort_t* xt   = (ushort_t*)(ws + XT_OFF);
    ushort_t* o1   = (ushort_t*)(ws + O1_OFF);
    ushort_t* kbuf = (ushort_t*)(ws + KB_OFF);

    hipMemsetAsync(gapsum, 0, 32768, stream);
    transpose_gap_kernel<<<dim3(32, 8, 32), 256, 0, stream>>>(x, xt, gapsum);
    router_linear_kernel<<<1, 256, 0, stream>>>(gapsum, rw, rb, r);
    combine_kernel<<<dim3(512, 4), 256, 0, stream>>>(w1, r, kbuf);
    gemm_conv<0><<<512, 256, 0, stream>>>(xt, kbuf, (void*)o1, g1, b1, m1, v1, nullptr);
    combine_kernel<<<dim3(512, 4), 256, 0, stream>>>(w2, r, kbuf);
    gemm_conv<1><<<512, 256, 0, stream>>>(o1, kbuf, d_out, g2, b2, m2, v2, xt);
}

// Round 9
// 231.126 us; speedup vs baseline: 1.3978x; 1.0377x over previous
//
#include <hip/hip_runtime.h>

typedef unsigned short ushort_t;
typedef __attribute__((ext_vector_type(8))) __bf16 bf16x8;
typedef __attribute__((ext_vector_type(4))) float f32x4;
typedef __attribute__((ext_vector_type(4))) int i32x4;
typedef __attribute__((ext_vector_type(4))) unsigned short u16x4;

#define BN_EPS 1e-5f
#define EPAD 136  // epilogue [p][c] c-stride (272B row, 16B-aligned)

// counted waitcnt via inline asm (no builtin); memory clobber pins VMEM/LDS ops.
// barriers use the builtin (scheduler-aware, does NOT force a vmcnt drain).
#define BAR()    __builtin_amdgcn_s_barrier()
#define VMCNT4() asm volatile("s_waitcnt vmcnt(4)" ::: "memory")
#define VMCNT0() asm volatile("s_waitcnt vmcnt(0)" ::: "memory")
#define LGKM0()  asm volatile("s_waitcnt lgkmcnt(0)" ::: "memory")

__device__ __forceinline__ ushort_t f2bf(float f) {
    union { float f; unsigned u; } v; v.f = f;
    unsigned r = v.u + 0x7FFFu + ((v.u >> 16) & 1u);
    return (ushort_t)(r >> 16);
}
__device__ __forceinline__ float bf2f(ushort_t h) {
    union { unsigned u; float f; } v; v.u = ((unsigned)h) << 16; return v.f;
}

// async 16B global->LDS copy; LDS dst is wave-uniform base (+lane*16 by HW)
__device__ __forceinline__ void async_cp16(const ushort_t* g, ushort_t* l) {
    __builtin_amdgcn_global_load_lds(
        (const __attribute__((address_space(1))) unsigned int*)g,
        (__attribute__((address_space(3))) unsigned int*)l, 16, 0, 0);
}

// ---------------- transpose+cast+GAP: x[b][c][p] f32 -> xt[b][p][c] bf16, partial GAP sums ----------------
// Vectorized: float4 loads (16B/lane), u16x4 stores (8B/lane). GAP via 8-lane shfl reduce.
__global__ void transpose_gap_kernel(const float* __restrict__ x, ushort_t* __restrict__ xt,
                                     float* __restrict__ gapsum) {
    __shared__ float tile[32][33]; // [c][p], +1 pad
    int b = blockIdx.z, c0 = blockIdx.y * 32, p0 = blockIdx.x * 32;
    int t = threadIdx.x;
    int c = t >> 3, q = t & 7;         // c 0..31, q = p-quad 0..7
    f32x4 v = *(const f32x4*)(x + ((long)b * 256 + c0 + c) * 1024 + p0 + q * 4);
    tile[c][q * 4 + 0] = v[0];
    tile[c][q * 4 + 1] = v[1];
    tile[c][q * 4 + 2] = v[2];
    tile[c][q * 4 + 3] = v[3];
    float ps = v[0] + v[1] + v[2] + v[3];
    ps += __shfl_down(ps, 4, 8);
    ps += __shfl_down(ps, 2, 8);
    ps += __shfl_down(ps, 1, 8);
    if (q == 0) atomicAdd(&gapsum[b * 256 + c0 + c], ps);
    __syncthreads();
    int p = t >> 3, coff = (t & 7) * 4; // p 0..31, 4 consecutive c per lane
    u16x4 pk;
    #pragma unroll
    for (int i = 0; i < 4; ++i) pk[i] = f2bf(tile[coff + i][p]);
    *(u16x4*)(xt + ((long)b * 1024 + p0 + p) * 256 + c0 + coff) = pk;
}

// ---------------- router linear: r[b,e] = sigmoid(gap/1024 . rw[e] + rb[e]) ----------------
// One wave per (b,e) dot: 256 blocks x 64 lanes, 4 elems/lane + shfl reduce.
// (was: 1 block, 256 serial 256-length dots -> whole GPU idle ~10-15us)
__global__ void router_linear_kernel(const float* __restrict__ gapsum, const float* __restrict__ rw,
                                     const float* __restrict__ rb, float* __restrict__ r) {
    int be = blockIdx.x;          // b*8 + e
    int b = be >> 3, e = be & 7;
    int lane = threadIdx.x;       // 0..63
    float s = 0.f;
    #pragma unroll
    for (int i = 0; i < 4; ++i)
        s += gapsum[b * 256 + lane + i * 64] * rw[e * 256 + lane + i * 64];
    #pragma unroll
    for (int off = 32; off; off >>= 1) s += __shfl_down(s, off, 64);
    if (lane == 0) r[be] = 1.f / (1.f + expf(-(s * (1.f / 1024.f) + rb[e])));
}

// ---------------- combine: ko[b][pos][g] = sum_e r[b,e]*w[e][g][pos], bf16 ----------------
// SINGLE PASS over all 32 b per g-chunk: w read exactly once total (18.9MB, was 4x=75.5MB).
// Stage-in: 128-g chunk of w (8e x 9p = 36.9KB f32) via coalesced float4 loads; 72 w in VGPRs.
// Compute+stage-out in 2 half-passes of 16 b: results bf16 into LDS (aliasing wl,
// 144 rows x 256B = exactly wl's 36864B), then 2304 x 16B coalesced global stores.
__global__ __launch_bounds__(256, 2) void combine_kernel(const float* __restrict__ w,
                                                         const float* __restrict__ r,
                                                         ushort_t* __restrict__ ko) {
    __shared__ float wl[9216]; // 36864 B; aliased as outb after wv reg-loads
    ushort_t* outb = (ushort_t*)wl;
    const int t = threadIdx.x;
    const int g0 = blockIdx.x * 128;

    // stage-in: 2304 float4, 9 per thread, coalesced ((g,p) raster IS w's layout)
    #pragma unroll
    for (int it = 0; it < 9; ++it) {
        int lin = it * 256 + t;
        int e = lin / 288, rem = lin - e * 288;
        f32x4 v = *(const f32x4*)(w + (long)e * 589824 + (long)g0 * 9 + rem * 4);
        *(f32x4*)(&wl[lin * 4]) = v;
    }
    __syncthreads();

    const int g = t & 127;
    const int half = t >> 7;   // wave-uniform (waves 0,1 -> 0; waves 2,3 -> 1)
    float wv[8][9];
    #pragma unroll
    for (int e = 0; e < 8; ++e)
        #pragma unroll
        for (int p = 0; p < 9; ++p)
            wv[e][p] = wl[e * 1152 + g * 9 + p];
    __syncthreads(); // all wl reads done -> safe to alias as outb

    #pragma unroll
    for (int hb = 0; hb < 2; ++hb) { // 16 b per half-pass
        #pragma unroll
        for (int j = 0; j < 8; ++j) {
            int b16 = half * 8 + j;       // 0..15 within pass
            int b = hb * 16 + b16;
            float rv[8];
            #pragma unroll
            for (int e = 0; e < 8; ++e) rv[e] = r[b * 8 + e];
            #pragma unroll
            for (int p = 0; p < 9; ++p) {
                float s = 0.f;
                #pragma unroll
                for (int e = 0; e < 8; ++e) s += rv[e] * wv[e][p];
                outb[(b16 * 9 + p) * 128 + g] = f2bf(s); // 2B LDS scatter: 2-way, free
            }
        }
        __syncthreads();
        // stage-out: 16b x 9p x 128g bf16 = 2304 16B chunks, 9 per thread, coalesced
        #pragma unroll
        for (int it = 0; it < 9; ++it) {
            int idx = it * 256 + t;           // 0..2303
            int row = idx >> 4, off = idx & 15; // row = b16*9+p (0..143)
            int b16 = row / 9, p = row - b16 * 9;
            i32x4 v = *(i32x4*)(&outb[row * 128 + off * 8]);
            *(i32x4*)(ko + ((long)((hb * 16 + b16) * 9 + p)) * 65536 + g0 + off * 8) = v;
        }
        __syncthreads(); // before next half-pass overwrites outb
    }
}

// ---------------- implicit-GEMM conv 3x3 (pad 1), per-sample weights ----------------
// Round-3-verified structure (41.6-43 us at full clocks): A staged via global_load_lds into
// XOR-swizzled ldsA double buffer; counted-vmcnt 2-barrier-per-iter schedule. Direct-A
// (round 6) was 2x WORSE: per-lane fragment gather = transaction-bound.
// Grid: 512 blocks, XCD-swizzled (id%8 = b%8 -> L2 reuse of kbank/x).
// LDS (16B chunks, XOR-swizzled, written only by global_load_lds):
//   ldsB: halo [6][34] rows x 8 k-chunks; slot(pi,j) = pi*8 + (j ^ (pi&7))
//   ldsA: 2 x (128 rows x 8 k-chunks); slot(row,j) = row*8 + (j ^ (row&7))
// MODE 0: out = bf16 relu(bn(conv)) [b][p][c];  MODE 1: out = f32 relu(bn(conv)+resid) [b][c][p]
template <int MODE>
__global__ __launch_bounds__(256, 2) void gemm_conv(
    const ushort_t* __restrict__ xin,   // [B][1024][256] bf16
    const ushort_t* __restrict__ kbank, // [B][9][256][256] bf16
    void* __restrict__ outp,
    const float* __restrict__ gam, const float* __restrict__ bet,
    const float* __restrict__ mu, const float* __restrict__ var,
    const ushort_t* __restrict__ residt) { // [B][1024][256] bf16 (MODE 1 only)
    __shared__ ushort_t smem[29440]; // ldsB: [0,13056) ; ldsA: [13056, 13056+16384)
    ushort_t* ldsB = smem;
    ushort_t* ldsA = smem + 13056;

    const int t = threadIdx.x;
    const int lane = t & 63;
    const int lane15 = lane & 15;
    const int quad = lane >> 4;
    const int wv = t >> 6;
    // XCD swizzle decode
    const int id = blockIdx.x;           // 0..511
    const int q  = id >> 3;              // mt + 2*nt + 16*(b>>3)
    const int mt = q & 1;
    const int nt = (q >> 1) & 7;
    const int b  = (id & 7) + ((q >> 4) << 3);
    const int h0 = nt * 4;
    const int p0 = nt * 128;
    const int mw0 = (wv >> 1) * 64;
    const int nw0 = (wv & 1) * 64;
    const int wbase = t & ~63;

    f32x4 acc[4][4];
    #pragma unroll
    for (int i = 0; i < 4; ++i)
        #pragma unroll
        for (int j = 0; j < 4; ++j) acc[i][j] = 0.f;

    // pre-zero (once; never overwritten): border cols w'=0,33 for all 6 rows
    if (t < 96) {
        int rix = t >> 3, j = t & 7;
        int pi = (rix >> 1) * 34 + (rix & 1) * 33;
        i32x4 z = 0;
        *(i32x4*)(&ldsB[(pi * 8 + j) * 8]) = z;
    }
    // pre-zero invalid-h interior rows (boundary blocks only; skipped by stageB)
    if (nt == 0) { i32x4 z = 0; *(i32x4*)(&ldsB[(8 + t) * 8]) = z; }                 // hh=0
    if (nt == 7) { i32x4 z = 0; *(i32x4*)(&ldsB[((5 * 34 + 1) * 8 + t) * 8]) = z; }  // hh=5

    const long xbase = (long)b * 1024 * 256;
    const long kbase = (long)b * 9 * 65536;

    auto stageB = [&](int kc) {
        #pragma unroll
        for (int hh = 0; hh < 6; ++hh) {
            int hg = h0 + hh - 1;
            if (hg < 0 || hg >= 32) continue; // block-uniform
            int ww = t >> 3;
            int pi = hh * 34 + 1 + ww;
            int jd = (t & 7) ^ (pi & 7);
            async_cp16(xin + xbase + (long)(hg * 32 + ww) * 256 + kc * 64 + jd * 8,
                       ldsB + ((hh * 34 + 1) * 8 + wbase) * 8);
        }
    };
    auto stageA = [&](int kc, int pos, int buf) {
        const ushort_t* srcA = kbank + kbase + (long)pos * 65536 + (long)mt * 32768 + kc * 64;
        ushort_t* base = ldsA + buf * 8192;
        #pragma unroll
        for (int it = 0; it < 4; ++it) {
            int s = it * 256 + t;
            int row = s >> 3;
            int k8 = (s & 7) ^ (row & 7);
            async_cp16(srcA + (long)row * 256 + k8 * 8, base + (it * 256 + wbase) * 8);
        }
    };

    stageB(0);
    stageA(0, 0, 0);
    __syncthreads(); // prologue: zero-fills + B tile + first A landed/published

    int par = 0;
    for (int kc = 0; kc < 4; ++kc) {
        for (int pos = 0; pos < 9; ++pos) {
            const bool last = (kc == 3 && pos == 8);
            if (!last) {
                int nk = kc, np = pos + 1;
                if (np == 9) { np = 0; ++nk; }
                stageA(nk, np, par ^ 1);   // 4 loads into buf[par^1]
                VMCNT4();                   // all-but-newest-4: buf[par] (+B at kc edge) landed
            } else {
                VMCNT0();
            }
            BAR();                          // bar_pub: stage data visible

            const int dh = pos / 3 - 1, dw = pos % 3 - 1;
            const ushort_t* ab = ldsA + par * 8192;
            bf16x8 af[2][4], bfr[2][4];
            #pragma unroll
            for (int kb = 0; kb < 2; ++kb) {
                int jk = kb * 4 + quad;
                #pragma unroll
                for (int mf = 0; mf < 4; ++mf) {
                    int row = mw0 + mf * 16 + lane15;
                    af[kb][mf] = *(const bf16x8*)(ab + (row * 8 + (jk ^ (row & 7))) * 8);
                }
                #pragma unroll
                for (int nf = 0; nf < 4; ++nf) {
                    int n = nw0 + nf * 16 + lane15;
                    int pi = ((n >> 5) + 1 + dh) * 34 + (n & 31) + 1 + dw;
                    bfr[kb][nf] = *(const bf16x8*)(&ldsB[(pi * 8 + (jk ^ (pi & 7))) * 8]);
                }
            }
            LGKM0();                        // own ds_reads retired
            BAR();                          // bar_rd: all waves done reading buf[par]/ldsB

            if (pos == 8 && kc < 3) stageB(kc + 1); // safe after bar_rd; lands by next vmcnt+bar

            __builtin_amdgcn_s_setprio(1);
            #pragma unroll
            for (int kb = 0; kb < 2; ++kb)
                #pragma unroll
                for (int mf = 0; mf < 4; ++mf)
                    #pragma unroll
                    for (int nf = 0; nf < 4; ++nf)
                        acc[mf][nf] = __builtin_amdgcn_mfma_f32_16x16x32_bf16(af[kb][mf], bfr[kb][nf], acc[mf][nf], 0, 0, 0);
            __builtin_amdgcn_s_setprio(0);
            par ^= 1;
        }
    }

    // residual prefetch (MODE 1): bf16 from xt, 4 consecutive c per acc frag
    u16x4 rres[4][4];
    if (MODE == 1) {
        #pragma unroll
        for (int mf = 0; mf < 4; ++mf)
            #pragma unroll
            for (int nf = 0; nf < 4; ++nf) {
                int p = p0 + nw0 + nf * 16 + lane15;
                int cb = mt * 128 + mw0 + mf * 16 + quad * 4;
                rres[mf][nf] = *(const u16x4*)(residt + ((long)b * 1024 + p) * 256 + cb);
            }
    }

    // BN scale/shift for this lane's 16 c_out values
    float sc[4][4], sh[4][4];
    #pragma unroll
    for (int mf = 0; mf < 4; ++mf)
        #pragma unroll
        for (int i = 0; i < 4; ++i) {
            int c = mt * 128 + mw0 + mf * 16 + quad * 4 + i;
            float s = gam[c] * rsqrtf(var[c] + BN_EPS);
            sc[mf][i] = s;
            sh[mf][i] = bet[c] - mu[c] * s;
        }

    if (MODE == 0) {
        __syncthreads();
        ushort_t* ldsE = smem; // [128 p][EPAD c]
        #pragma unroll
        for (int mf = 0; mf < 4; ++mf)
            #pragma unroll
            for (int nf = 0; nf < 4; ++nf) {
                int pl = nw0 + nf * 16 + lane15;
                int cb = mw0 + mf * 16 + quad * 4;
                u16x4 pk;
                #pragma unroll
                for (int i = 0; i < 4; ++i) {
                    float v = acc[mf][nf][i] * sc[mf][i] + sh[mf][i];
                    pk[i] = f2bf(fmaxf(v, 0.f));
                }
                *(u16x4*)(&ldsE[pl * EPAD + cb]) = pk;
            }
        __syncthreads();
        ushort_t* op = (ushort_t*)outp;
        #pragma unroll
        for (int it = 0; it < 8; ++it) {
            int s = t + it * 256;
            int row = s >> 4, l16 = s & 15;
            i32x4 v = *(i32x4*)(&ldsE[row * EPAD + l16 * 8]);
            *(i32x4*)(op + ((long)b * 1024 + p0 + row) * 256 + mt * 128 + l16 * 8) = v;
        }
    } else {
        float* op = (float*)outp;
        #pragma unroll
        for (int mf = 0; mf < 4; ++mf)
            #pragma unroll
            for (int nf = 0; nf < 4; ++nf) {
                int p = p0 + nw0 + nf * 16 + lane15;
                #pragma unroll
                for (int i = 0; i < 4; ++i) {
                    int c = mt * 128 + mw0 + mf * 16 + quad * 4 + i;
                    float v = acc[mf][nf][i] * sc[mf][i] + sh[mf][i] + bf2f(rres[mf][nf][i]);
                    op[((long)b * 256 + c) * 1024 + p] = fmaxf(v, 0.f);
                }
            }
    }
}

extern "C" void kernel_launch(void* const* d_in, const int* in_sizes, int n_in,
                              void* d_out, int out_size, void* d_ws, size_t ws_size,
                              hipStream_t stream) {
    const float* x  = (const float*)d_in[0];
    const float* rw = (const float*)d_in[1];
    const float* rb = (const float*)d_in[2];
    const float* w1 = (const float*)d_in[3];
    const float* w2 = (const float*)d_in[4];
    const float* g1 = (const float*)d_in[5];
    const float* b1 = (const float*)d_in[6];
    const float* m1 = (const float*)d_in[7];
    const float* v1 = (const float*)d_in[8];
    const float* g2 = (const float*)d_in[9];
    const float* b2 = (const float*)d_in[10];
    const float* m2 = (const float*)d_in[11];
    const float* v2 = (const float*)d_in[12];

    // ws layout: r [0,1KB) | gapsum [4096, +32KB) | xt | o1 | kbuf (reused for both layers)
    const size_t GAP_OFF = 4096;
    const size_t XT_OFF  = 36864;
    const size_t O1_OFF  = XT_OFF + (size_t)16777216;
    const size_t KB_OFF  = O1_OFF + (size_t)16777216;
    const size_t NEED    = KB_OFF + (size_t)32 * 9 * 65536 * 2;
    if (ws_size < NEED) return;

    char* ws = (char*)d_ws;
    float* r       = (float*)ws;
    float* gapsum  = (float*)(ws + GAP_OFF);
    ushort_t* xt   = (ushort_t*)(ws + XT_OFF);
    ushort_t* o1   = (ushort_t*)(ws + O1_OFF);
    ushort_t* kbuf = (ushort_t*)(ws + KB_OFF);

    hipMemsetAsync(gapsum, 0, 32768, stream);
    transpose_gap_kernel<<<dim3(32, 8, 32), 256, 0, stream>>>(x, xt, gapsum);
    router_linear_kernel<<<256, 64, 0, stream>>>(gapsum, rw, rb, r);
    combine_kernel<<<dim3(512), 256, 0, stream>>>(w1, r, kbuf);
    gemm_conv<0><<<512, 256, 0, stream>>>(xt, kbuf, (void*)o1, g1, b1, m1, v1, nullptr);
    combine_kernel<<<dim3(512), 256, 0, stream>>>(w2, r, kbuf);
    gemm_conv<1><<<512, 256, 0, stream>>>(o1, kbuf, d_out, g2, b2, m2, v2, xt);
}

// Round 10
// 227.395 us; speedup vs baseline: 1.4208x; 1.0164x over previous
//
#include <hip/hip_runtime.h>

typedef unsigned short ushort_t;
typedef __attribute__((ext_vector_type(8))) __bf16 bf16x8;
typedef __attribute__((ext_vector_type(4))) float f32x4;
typedef __attribute__((ext_vector_type(4))) int i32x4;
typedef __attribute__((ext_vector_type(4))) unsigned short u16x4;

#define BN_EPS 1e-5f
#define EPAD 136  // epilogue [p][c] c-stride (272B row, 16B-aligned)

// counted waitcnt via inline asm (no builtin); memory clobber pins VMEM/LDS ops.
// barriers use the builtin (scheduler-aware, does NOT force a vmcnt drain).
#define BAR()    __builtin_amdgcn_s_barrier()
#define VMCNT4() asm volatile("s_waitcnt vmcnt(4)" ::: "memory")
#define VMCNT0() asm volatile("s_waitcnt vmcnt(0)" ::: "memory")
#define LGKM0()  asm volatile("s_waitcnt lgkmcnt(0)" ::: "memory")

__device__ __forceinline__ ushort_t f2bf(float f) {
    union { float f; unsigned u; } v; v.f = f;
    unsigned r = v.u + 0x7FFFu + ((v.u >> 16) & 1u);
    return (ushort_t)(r >> 16);
}
__device__ __forceinline__ float bf2f(ushort_t h) {
    union { unsigned u; float f; } v; v.u = ((unsigned)h) << 16; return v.f;
}

// async 16B global->LDS copy; LDS dst is wave-uniform base (+lane*16 by HW)
__device__ __forceinline__ void async_cp16(const ushort_t* g, ushort_t* l) {
    __builtin_amdgcn_global_load_lds(
        (const __attribute__((address_space(1))) unsigned int*)g,
        (__attribute__((address_space(3))) unsigned int*)l, 16, 0, 0);
}

// ---------------- transpose+cast+GAP: x[b][c][p] f32 -> xt[b][p][c] bf16, GAP partials ----------------
// Vectorized: float4 loads (16B/lane), u16x4 stores (8B/lane). GAP partials go to
// gpart[(b*256+c)*32 + px] via PLAIN stores (each slot written exactly once by its
// p-block) — removes both the atomics and the hipMemsetAsync dispatch.
__global__ void transpose_gap_kernel(const float* __restrict__ x, ushort_t* __restrict__ xt,
                                     float* __restrict__ gpart) {
    __shared__ float tile[32][33]; // [c][p], +1 pad
    int b = blockIdx.z, c0 = blockIdx.y * 32, p0 = blockIdx.x * 32;
    int t = threadIdx.x;
    int c = t >> 3, q = t & 7;         // c 0..31, q = p-quad 0..7
    f32x4 v = *(const f32x4*)(x + ((long)b * 256 + c0 + c) * 1024 + p0 + q * 4);
    tile[c][q * 4 + 0] = v[0];
    tile[c][q * 4 + 1] = v[1];
    tile[c][q * 4 + 2] = v[2];
    tile[c][q * 4 + 3] = v[3];
    float ps = v[0] + v[1] + v[2] + v[3];
    ps += __shfl_down(ps, 4, 8);
    ps += __shfl_down(ps, 2, 8);
    ps += __shfl_down(ps, 1, 8);
    if (q == 0) gpart[((long)b * 256 + c0 + c) * 32 + blockIdx.x] = ps;
    __syncthreads();
    int p = t >> 3, coff = (t & 7) * 4; // p 0..31, 4 consecutive c per lane
    u16x4 pk;
    #pragma unroll
    for (int i = 0; i < 4; ++i) pk[i] = f2bf(tile[coff + i][p]);
    *(u16x4*)(xt + ((long)b * 1024 + p0 + p) * 256 + c0 + coff) = pk;
}

// ---------------- router linear: r[b,e] = sigmoid(gap/1024 . rw[e] + rb[e]) ----------------
// One wave per (b,e): sums the 32 p-block partials per c (contiguous 128B runs, f32x4),
// then the c-dot via shfl reduce.
__global__ void router_linear_kernel(const float* __restrict__ gpart, const float* __restrict__ rw,
                                     const float* __restrict__ rb, float* __restrict__ r) {
    int be = blockIdx.x;          // b*8 + e
    int b = be >> 3, e = be & 7;
    int lane = threadIdx.x;       // 0..63
    float s = 0.f;
    #pragma unroll
    for (int i = 0; i < 4; ++i) {
        int c = lane + i * 64;
        const f32x4* gp = (const f32x4*)(gpart + ((long)b * 256 + c) * 32);
        float g = 0.f;
        #pragma unroll
        for (int j = 0; j < 8; ++j) { f32x4 v = gp[j]; g += (v[0] + v[1]) + (v[2] + v[3]); }
        s += g * rw[e * 256 + c];
    }
    #pragma unroll
    for (int off = 32; off; off >>= 1) s += __shfl_down(s, off, 64);
    if (lane == 0) r[be] = 1.f / (1.f + expf(-(s * (1.f / 1024.f) + rb[e])));
}

// ---------------- combine: ko[b][pos][g] = sum_e r[b,e]*w[e][g][pos], bf16 ----------------
// SINGLE PASS over all 32 b per g-chunk: w read exactly once total (18.9MB).
// Stage-in: 128-g chunk of w (8e x 9p = 36.9KB f32) via coalesced float4 loads; 72 w in VGPRs.
// Compute+stage-out in 2 half-passes of 16 b: results bf16 into LDS (aliasing wl),
// then 2304 x 16B coalesced global stores.
__global__ __launch_bounds__(256, 2) void combine_kernel(const float* __restrict__ w,
                                                         const float* __restrict__ r,
                                                         ushort_t* __restrict__ ko) {
    __shared__ float wl[9216]; // 36864 B; aliased as outb after wv reg-loads
    ushort_t* outb = (ushort_t*)wl;
    const int t = threadIdx.x;
    const int g0 = blockIdx.x * 128;

    // stage-in: 2304 float4, 9 per thread, coalesced ((g,p) raster IS w's layout)
    #pragma unroll
    for (int it = 0; it < 9; ++it) {
        int lin = it * 256 + t;
        int e = lin / 288, rem = lin - e * 288;
        f32x4 v = *(const f32x4*)(w + (long)e * 589824 + (long)g0 * 9 + rem * 4);
        *(f32x4*)(&wl[lin * 4]) = v;
    }
    __syncthreads();

    const int g = t & 127;
    const int half = t >> 7;   // wave-uniform
    float wv[8][9];
    #pragma unroll
    for (int e = 0; e < 8; ++e)
        #pragma unroll
        for (int p = 0; p < 9; ++p)
            wv[e][p] = wl[e * 1152 + g * 9 + p];
    __syncthreads(); // all wl reads done -> safe to alias as outb

    #pragma unroll
    for (int hb = 0; hb < 2; ++hb) { // 16 b per half-pass
        #pragma unroll
        for (int j = 0; j < 8; ++j) {
            int b16 = half * 8 + j;       // 0..15 within pass
            int b = hb * 16 + b16;
            float rv[8];
            #pragma unroll
            for (int e = 0; e < 8; ++e) rv[e] = r[b * 8 + e];
            #pragma unroll
            for (int p = 0; p < 9; ++p) {
                float s = 0.f;
                #pragma unroll
                for (int e = 0; e < 8; ++e) s += rv[e] * wv[e][p];
                outb[(b16 * 9 + p) * 128 + g] = f2bf(s); // 2B LDS scatter: 2-way, free
            }
        }
        __syncthreads();
        // stage-out: 16b x 9p x 128g bf16 = 2304 16B chunks, 9 per thread, coalesced
        #pragma unroll
        for (int it = 0; it < 9; ++it) {
            int idx = it * 256 + t;           // 0..2303
            int row = idx >> 4, off = idx & 15; // row = b16*9+p (0..143)
            int b16 = row / 9, p = row - b16 * 9;
            i32x4 v = *(i32x4*)(&outb[row * 128 + off * 8]);
            *(i32x4*)(ko + ((long)((hb * 16 + b16) * 9 + p)) * 65536 + g0 + off * 8) = v;
        }
        __syncthreads(); // before next half-pass overwrites outb
    }
}

// ---------------- implicit-GEMM conv 3x3 (pad 1), per-sample weights ----------------
// NEW: 3-buffer ldsA rotation -> ONE barrier per iteration (was 2). A buffer written at
// iter i is read at i+1 and next rewritten at i+3: barrier(i+2) already guarantees all
// reads done (trailing LGKM0 retires own reads pre-barrier), so the read-fence BAR is
// dropped on non-edge iterations. Waves drift within the window -> one wave's ds_reads
// overlap another's MFMAs (was lockstep: all-read then all-MFMA, pipes serialized).
// kc-edge keeps the extra LGKM0+BAR to protect the single ldsB halo tile.
// vmcnt(4) at each wait retires prev stageA (+stageB at edges): outstanding = newA(4)
// [+B(6)+prevA(4)] -> wait-to-4 leaves only the just-issued stage in flight.
// LDS 75264B (ldsB 26112 + 3x16384): 2 blocks/CU = 150KB <= 160KB, occupancy kept.
// MODE 0: out = bf16 relu(bn(conv)) [b][p][c];  MODE 1: out = f32 relu(bn(conv)+resid) [b][c][p]
template <int MODE>
__global__ __launch_bounds__(256, 2) void gemm_conv(
    const ushort_t* __restrict__ xin,   // [B][1024][256] bf16
    const ushort_t* __restrict__ kbank, // [B][9][256][256] bf16
    void* __restrict__ outp,
    const float* __restrict__ gam, const float* __restrict__ bet,
    const float* __restrict__ mu, const float* __restrict__ var,
    const ushort_t* __restrict__ residt) { // [B][1024][256] bf16 (MODE 1 only)
    __shared__ ushort_t smem[37632]; // ldsB: [0,13056) ; ldsA: 3 x 4096 at [13056, 37632)
    ushort_t* ldsB = smem;
    ushort_t* ldsA = smem + 13056;

    const int t = threadIdx.x;
    const int lane = t & 63;
    const int lane15 = lane & 15;
    const int quad = lane >> 4;
    const int wv = t >> 6;
    // XCD swizzle decode
    const int id = blockIdx.x;           // 0..511
    const int q  = id >> 3;              // mt + 2*nt + 16*(b>>3)
    const int mt = q & 1;
    const int nt = (q >> 1) & 7;
    const int b  = (id & 7) + ((q >> 4) << 3);
    const int h0 = nt * 4;
    const int p0 = nt * 128;
    const int mw0 = (wv >> 1) * 64;
    const int nw0 = (wv & 1) * 64;
    const int wbase = t & ~63;

    f32x4 acc[4][4];
    #pragma unroll
    for (int i = 0; i < 4; ++i)
        #pragma unroll
        for (int j = 0; j < 4; ++j) acc[i][j] = 0.f;

    // pre-zero (once; never overwritten): border cols w'=0,33 for all 6 rows
    if (t < 96) {
        int rix = t >> 3, j = t & 7;
        int pi = (rix >> 1) * 34 + (rix & 1) * 33;
        i32x4 z = 0;
        *(i32x4*)(&ldsB[(pi * 8 + j) * 8]) = z;
    }
    // pre-zero invalid-h interior rows (boundary blocks only; skipped by stageB)
    if (nt == 0) { i32x4 z = 0; *(i32x4*)(&ldsB[(8 + t) * 8]) = z; }                 // hh=0
    if (nt == 7) { i32x4 z = 0; *(i32x4*)(&ldsB[((5 * 34 + 1) * 8 + t) * 8]) = z; }  // hh=5

    const long xbase = (long)b * 1024 * 256;
    const long kbase = (long)b * 9 * 65536;

    auto stageB = [&](int kc) {
        #pragma unroll
        for (int hh = 0; hh < 6; ++hh) {
            int hg = h0 + hh - 1;
            if (hg < 0 || hg >= 32) continue; // block-uniform
            int ww = t >> 3;
            int pi = hh * 34 + 1 + ww;
            int jd = (t & 7) ^ (pi & 7);
            async_cp16(xin + xbase + (long)(hg * 32 + ww) * 256 + kc * 64 + jd * 8,
                       ldsB + ((hh * 34 + 1) * 8 + wbase) * 8);
        }
    };
    auto stageA = [&](int kc, int pos, int buf) {
        const ushort_t* srcA = kbank + kbase + (long)pos * 65536 + (long)mt * 32768 + kc * 64;
        ushort_t* base = ldsA + buf * 8192;
        #pragma unroll
        for (int it = 0; it < 4; ++it) {
            int s = it * 256 + t;
            int row = s >> 3;
            int k8 = (s & 7) ^ (row & 7);
            async_cp16(srcA + (long)row * 256 + k8 * 8, base + (it * 256 + wbase) * 8);
        }
    };

    stageB(0);
    stageA(0, 0, 0);
    __syncthreads(); // prologue: zero-fills + B tile + first A landed/published

    int cur = 0;
    for (int kc = 0; kc < 4; ++kc) {
        for (int pos = 0; pos < 9; ++pos) {
            const bool last = (kc == 3 && pos == 8);
            const int nxt = (cur == 2) ? 0 : cur + 1;
            if (!last) {
                int nk = kc, np = pos + 1;
                if (np == 9) { np = 0; ++nk; }
                stageA(nk, np, nxt);       // write buf[nxt]: all reads of it done >=2 barriers ago
                VMCNT4();                   // retires prev stageA (+stageB at kc edge)
            } else {
                VMCNT0();
            }
            BAR();                          // buf[cur] (+ new ldsB at kc edge) published

            const int dh = pos / 3 - 1, dw = pos % 3 - 1;
            const ushort_t* ab = ldsA + cur * 8192;
            bf16x8 af[2][4], bfr[2][4];
            #pragma unroll
            for (int kb = 0; kb < 2; ++kb) {
                int jk = kb * 4 + quad;
                #pragma unroll
                for (int mf = 0; mf < 4; ++mf) {
                    int row = mw0 + mf * 16 + lane15;
                    af[kb][mf] = *(const bf16x8*)(ab + (row * 8 + (jk ^ (row & 7))) * 8);
                }
                #pragma unroll
                for (int nf = 0; nf < 4; ++nf) {
                    int n = nw0 + nf * 16 + lane15;
                    int pi = ((n >> 5) + 1 + dh) * 34 + (n & 31) + 1 + dw;
                    bfr[kb][nf] = *(const bf16x8*)(&ldsB[(pi * 8 + (jk ^ (pi & 7))) * 8]);
                }
            }
            if (pos == 8 && kc < 3) {
                LGKM0();            // all own ldsB reads retired
                BAR();              // every wave done with this kc's B tile
                stageB(kc + 1);     // overwrite ldsB; lands by next VMCNT4+BAR
            }

            __builtin_amdgcn_s_setprio(1);
            #pragma unroll
            for (int kb = 0; kb < 2; ++kb)
                #pragma unroll
                for (int mf = 0; mf < 4; ++mf)
                    #pragma unroll
                    for (int nf = 0; nf < 4; ++nf)
                        acc[mf][nf] = __builtin_amdgcn_mfma_f32_16x16x32_bf16(af[kb][mf], bfr[kb][nf], acc[mf][nf], 0, 0, 0);
            __builtin_amdgcn_s_setprio(0);
            LGKM0();                // ~free (MFMA deps already retired reads); strictly
                                    // guarantees no in-flight read crosses the next BAR
            cur = nxt;
        }
    }

    // residual prefetch (MODE 1): bf16 from xt, 4 consecutive c per acc frag
    u16x4 rres[4][4];
    if (MODE == 1) {
        #pragma unroll
        for (int mf = 0; mf < 4; ++mf)
            #pragma unroll
            for (int nf = 0; nf < 4; ++nf) {
                int p = p0 + nw0 + nf * 16 + lane15;
                int cb = mt * 128 + mw0 + mf * 16 + quad * 4;
                rres[mf][nf] = *(const u16x4*)(residt + ((long)b * 1024 + p) * 256 + cb);
            }
    }

    // BN scale/shift for this lane's 16 c_out values
    float sc[4][4], sh[4][4];
    #pragma unroll
    for (int mf = 0; mf < 4; ++mf)
        #pragma unroll
        for (int i = 0; i < 4; ++i) {
            int c = mt * 128 + mw0 + mf * 16 + quad * 4 + i;
            float s = gam[c] * rsqrtf(var[c] + BN_EPS);
            sc[mf][i] = s;
            sh[mf][i] = bet[c] - mu[c] * s;
        }

    if (MODE == 0) {
        __syncthreads();
        ushort_t* ldsE = smem; // [128 p][EPAD c]
        #pragma unroll
        for (int mf = 0; mf < 4; ++mf)
            #pragma unroll
            for (int nf = 0; nf < 4; ++nf) {
                int pl = nw0 + nf * 16 + lane15;
                int cb = mw0 + mf * 16 + quad * 4;
                u16x4 pk;
                #pragma unroll
                for (int i = 0; i < 4; ++i) {
                    float v = acc[mf][nf][i] * sc[mf][i] + sh[mf][i];
                    pk[i] = f2bf(fmaxf(v, 0.f));
                }
                *(u16x4*)(&ldsE[pl * EPAD + cb]) = pk;
            }
        __syncthreads();
        ushort_t* op = (ushort_t*)outp;
        #pragma unroll
        for (int it = 0; it < 8; ++it) {
            int s = t + it * 256;
            int row = s >> 4, l16 = s & 15;
            i32x4 v = *(i32x4*)(&ldsE[row * EPAD + l16 * 8]);
            *(i32x4*)(op + ((long)b * 1024 + p0 + row) * 256 + mt * 128 + l16 * 8) = v;
        }
    } else {
        float* op = (float*)outp;
        #pragma unroll
        for (int mf = 0; mf < 4; ++mf)
            #pragma unroll
            for (int nf = 0; nf < 4; ++nf) {
                int p = p0 + nw0 + nf * 16 + lane15;
                #pragma unroll
                for (int i = 0; i < 4; ++i) {
                    int c = mt * 128 + mw0 + mf * 16 + quad * 4 + i;
                    float v = acc[mf][nf][i] * sc[mf][i] + sh[mf][i] + bf2f(rres[mf][nf][i]);
                    op[((long)b * 256 + c) * 1024 + p] = fmaxf(v, 0.f);
                }
            }
    }
}

extern "C" void kernel_launch(void* const* d_in, const int* in_sizes, int n_in,
                              void* d_out, int out_size, void* d_ws, size_t ws_size,
                              hipStream_t stream) {
    const float* x  = (const float*)d_in[0];
    const float* rw = (const float*)d_in[1];
    const float* rb = (const float*)d_in[2];
    const float* w1 = (const float*)d_in[3];
    const float* w2 = (const float*)d_in[4];
    const float* g1 = (const float*)d_in[5];
    const float* b1 = (const float*)d_in[6];
    const float* m1 = (const float*)d_in[7];
    const float* v1 = (const float*)d_in[8];
    const float* g2 = (const float*)d_in[9];
    const float* b2 = (const float*)d_in[10];
    const float* m2 = (const float*)d_in[11];
    const float* v2 = (const float*)d_in[12];

    // ws layout: r [0,1KB) | gpart [4096, +1MB) | xt | o1 | kbuf (reused for both layers)
    const size_t GP_OFF  = 4096;
    const size_t XT_OFF  = GP_OFF + (size_t)1048576;
    const size_t O1_OFF  = XT_OFF + (size_t)16777216;
    const size_t KB_OFF  = O1_OFF + (size_t)16777216;
    const size_t NEED    = KB_OFF + (size_t)32 * 9 * 65536 * 2;
    if (ws_size < NEED) return;

    char* ws = (char*)d_ws;
    float* r       = (float*)ws;
    float* gpart   = (float*)(ws + GP_OFF);
    ushort_t* xt   = (ushort_t*)(ws + XT_OFF);
    ushort_t* o1   = (ushort_t*)(ws + O1_OFF);
    ushort_t* kbuf = (ushort_t*)(ws + KB_OFF);

    transpose_gap_kernel<<<dim3(32, 8, 32), 256, 0, stream>>>(x, xt, gpart);
    router_linear_kernel<<<256, 64, 0, stream>>>(gpart, rw, rb, r);
    combine_kernel<<<dim3(512), 256, 0, stream>>>(w1, r, kbuf);
    gemm_conv<0><<<512, 256, 0, stream>>>(xt, kbuf, (void*)o1, g1, b1, m1, v1, nullptr);
    combine_kernel<<<dim3(512), 256, 0, stream>>>(w2, r, kbuf);
    gemm_conv<1><<<512, 256, 0, stream>>>(o1, kbuf, d_out, g2, b2, m2, v2, xt);
}